// Round 1
// baseline (614.551 us; speedup 1.0000x reference)
//
#include <hip/hip_runtime.h>
#include <hip/hip_bf16.h>

// Problem constants
#define NN 50000
#define EE 800000
#define HH 4
#define DD 64
#define HD 256
#define DIN 128

// ---------------- CSR build ----------------

__global__ void hist_kernel(const int* __restrict__ e0, int* __restrict__ cnt, int E) {
    int i = blockIdx.x * 256 + threadIdx.x;
    if (i < E) atomicAdd(&cnt[e0[i]], 1);
}

__global__ __launch_bounds__(1024) void scan_kernel(const int* __restrict__ cnt,
                                                    int* __restrict__ rp,
                                                    int* __restrict__ cur, int N) {
    __shared__ int buf[2][1024];
    int t = threadIdx.x;
    if (t == 0) rp[0] = 0;
    int carry = 0;
    for (int base = 0; base < N; base += 1024) {
        int i = base + t;
        int v = (i < N) ? cnt[i] : 0;
        int sel = 0;
        buf[0][t] = v;
        __syncthreads();
        for (int off = 1; off < 1024; off <<= 1) {
            int nv = buf[sel][t];
            if (t >= off) nv += buf[sel][t - off];
            buf[sel ^ 1][t] = nv;
            __syncthreads();
            sel ^= 1;
        }
        int incl = buf[sel][t];
        int total = buf[sel][1023];
        if (i < N) {
            rp[i + 1] = carry + incl;
            cur[i] = carry + incl - v;  // exclusive prefix = write cursor
        }
        carry += total;
        __syncthreads();  // protect buf before next chunk overwrites
    }
}

__global__ void scatter_kernel(const int* __restrict__ e0, const int* __restrict__ e1,
                               int* __restrict__ cur, int* __restrict__ col, int E) {
    int i = blockIdx.x * 256 + threadIdx.x;
    if (i < E) {
        int pos = atomicAdd(&cur[e0[i]], 1);
        col[pos] = e1[i];
    }
}

// ---------------- GEMM: Y[n][m] = sum_k X[n][k]*W[m][k] + b[m] ----------------
// 64x64 tile, BK=16, 256 threads, 4x4 microtile, f32 vector FMA.

__global__ __launch_bounds__(256) void gemm_bias(const float* __restrict__ X,
                                                 const float* __restrict__ W,
                                                 const float* __restrict__ bias,
                                                 float* __restrict__ Y,
                                                 int Nrows, int K, int M) {
    __shared__ float As[16][68];
    __shared__ float Bs[16][68];
    const int t = threadIdx.x;
    const int tx = t & 15, ty = t >> 4;
    const int row0 = blockIdx.y * 64;
    const int col0 = blockIdx.x * 64;
    float acc[4][4] = {};

    for (int k0 = 0; k0 < K; k0 += 16) {
        int m = t >> 2;
        int kq = (t & 3) * 4;
        int r = row0 + m;
        float4 va = make_float4(0.f, 0.f, 0.f, 0.f);
        if (r < Nrows) va = *(const float4*)(X + (size_t)r * K + k0 + kq);
        As[kq + 0][m] = va.x; As[kq + 1][m] = va.y;
        As[kq + 2][m] = va.z; As[kq + 3][m] = va.w;
        float4 vb = *(const float4*)(W + (size_t)(col0 + m) * K + k0 + kq);
        Bs[kq + 0][m] = vb.x; Bs[kq + 1][m] = vb.y;
        Bs[kq + 2][m] = vb.z; Bs[kq + 3][m] = vb.w;
        __syncthreads();
#pragma unroll
        for (int k = 0; k < 16; ++k) {
            float a[4], b[4];
            *(float4*)a = *(const float4*)&As[k][ty * 4];
            *(float4*)b = *(const float4*)&Bs[k][tx * 4];
#pragma unroll
            for (int i = 0; i < 4; ++i)
#pragma unroll
                for (int j = 0; j < 4; ++j) acc[i][j] += a[i] * b[j];
        }
        __syncthreads();
    }
#pragma unroll
    for (int i = 0; i < 4; ++i) {
        int r = row0 + ty * 4 + i;
        if (r >= Nrows) break;
#pragma unroll
        for (int j = 0; j < 4; ++j) {
            int c = col0 + tx * 4 + j;
            Y[(size_t)r * M + c] = acc[i][j] + bias[c];
        }
    }
}

// ---------------- per-node attention scores ----------------
// s_l[n,h] = sum_d lrelu(h[n,h,d]*att[h,d]);  s_r with att[h,64+d]

__global__ __launch_bounds__(256) void scores_kernel(const float* __restrict__ hbuf,
                                                     const float* __restrict__ att,
                                                     float* __restrict__ sl,
                                                     float* __restrict__ sr) {
    int n = blockIdx.x;
    int t = threadIdx.x;
    int hh = t >> 6, d = t & 63;
    float v = hbuf[(size_t)n * HD + t];
    float pl = v * att[hh * 2 * DD + d];
    float pr = v * att[hh * 2 * DD + DD + d];
    pl = pl > 0.f ? pl : 0.01f * pl;
    pr = pr > 0.f ? pr : 0.01f * pr;
#pragma unroll
    for (int m = 32; m > 0; m >>= 1) {
        pl += __shfl_xor(pl, m);
        pr += __shfl_xor(pr, m);
    }
    if (d == 0) {
        sl[n * HH + hh] = pl;
        sr[n * HH + hh] = pr;
    }
}

// ---------------- gather aggregation (one node per block) ----------------

template <bool FINAL>
__global__ __launch_bounds__(256) void gather_kernel(const float* __restrict__ hbuf,
                                                     const int* __restrict__ rp,
                                                     const int* __restrict__ col,
                                                     const float* __restrict__ sl,
                                                     const float* __restrict__ sr,
                                                     float* __restrict__ out) {
    int n = blockIdx.x;
    int t = threadIdx.x;
    int hh = t >> 6;
    int start = rp[n], end = rp[n + 1];
    float my_sl = sl[n * HH + hh];
    float acc = 0.f, den = 0.f;
    __shared__ int cbuf[256];
    for (int base = start; base < end; base += 256) {
        int m = end - base;
        if (m > 256) m = 256;
        __syncthreads();
        if (t < m) cbuf[t] = col[base + t];
        __syncthreads();
        for (int j = 0; j < m; ++j) {
            int src = cbuf[j];
            float sv = __expf((my_sl + sr[src * HH + hh]) * 0.0078125f);  // 1/(2*64)
            acc += hbuf[(size_t)src * HD + t] * sv;
            den += sv;
        }
    }
    float r = acc / den;
    if (!FINAL) {
        out[(size_t)n * HD + t] = r;
    } else {
        __shared__ float red[256];
        red[t] = r;
        __syncthreads();
        if (t < DD)
            out[(size_t)n * DD + t] =
                0.25f * (red[t] + red[t + 64] + red[t + 128] + red[t + 192]);
    }
}

// ---------------- LayerNorm + LeakyReLU (in place), wave per row ----------------

__global__ __launch_bounds__(256) void ln_kernel(float* __restrict__ a,
                                                 const float* __restrict__ gamma,
                                                 const float* __restrict__ beta, int N) {
    int wave = threadIdx.x >> 6;
    int lane = threadIdx.x & 63;
    int row = blockIdx.x * 4 + wave;
    if (row >= N) return;
    float v[4];
    float s = 0.f;
#pragma unroll
    for (int i = 0; i < 4; ++i) {
        v[i] = a[(size_t)row * HD + i * 64 + lane];
        s += v[i];
    }
#pragma unroll
    for (int m = 32; m > 0; m >>= 1) s += __shfl_xor(s, m);
    float mu = s * (1.f / 256.f);
    float var = 0.f;
#pragma unroll
    for (int i = 0; i < 4; ++i) {
        float d = v[i] - mu;
        var += d * d;
    }
#pragma unroll
    for (int m = 32; m > 0; m >>= 1) var += __shfl_xor(var, m);
    var *= (1.f / 256.f);
    float rs = rsqrtf(var + 1e-5f);
#pragma unroll
    for (int i = 0; i < 4; ++i) {
        int c = i * 64 + lane;
        float y = (v[i] - mu) * rs * gamma[c] + beta[c];
        y = y > 0.f ? y : 0.01f * y;
        a[(size_t)row * HD + c] = y;
    }
}

// ---------------- launch ----------------

extern "C" void kernel_launch(void* const* d_in, const int* in_sizes, int n_in,
                              void* d_out, int out_size, void* d_ws, size_t ws_size,
                              hipStream_t stream) {
    const float* x     = (const float*)d_in[0];
    const int*   ei    = (const int*)d_in[1];   // (2, E): e0 then e1
    const float* W0    = (const float*)d_in[2];
    const float* b0    = (const float*)d_in[3];
    const float* W1    = (const float*)d_in[4];
    const float* b1    = (const float*)d_in[5];
    const float* att0  = (const float*)d_in[6];
    const float* att1  = (const float*)d_in[7];
    const float* gamma = (const float*)d_in[8];
    const float* beta  = (const float*)d_in[9];
    float* out = (float*)d_out;

    const int N = NN, E = EE;

    float* h_buf = (float*)d_ws;                       // N*256
    float* a_buf = h_buf + (size_t)N * HD;             // N*256
    float* sl    = a_buf + (size_t)N * HD;             // N*4
    float* sr    = sl + (size_t)N * HH;                // N*4
    int*   cnt   = (int*)(sr + (size_t)N * HH);        // N
    int*   rp    = cnt + N;                            // N+1
    int*   cur   = rp + N + 1;                         // N
    int*   col   = cur + N;                            // E

    const int* e0 = ei;
    const int* e1 = ei + E;

    // CSR build (same for both layers)
    hipMemsetAsync(cnt, 0, N * sizeof(int), stream);
    hist_kernel<<<(E + 255) / 256, 256, 0, stream>>>(e0, cnt, E);
    scan_kernel<<<1, 1024, 0, stream>>>(cnt, rp, cur, N);
    scatter_kernel<<<(E + 255) / 256, 256, 0, stream>>>(e0, e1, cur, col, E);

    // layer 0
    gemm_bias<<<dim3(HD / 64, (N + 63) / 64), 256, 0, stream>>>(x, W0, b0, h_buf, N, DIN, HD);
    scores_kernel<<<N, 256, 0, stream>>>(h_buf, att0, sl, sr);
    gather_kernel<false><<<N, 256, 0, stream>>>(h_buf, rp, col, sl, sr, a_buf);
    ln_kernel<<<(N + 3) / 4, 256, 0, stream>>>(a_buf, gamma, beta, N);

    // layer 1
    gemm_bias<<<dim3(HD / 64, (N + 63) / 64), 256, 0, stream>>>(a_buf, W1, b1, h_buf, N, HD, HD);
    scores_kernel<<<N, 256, 0, stream>>>(h_buf, att1, sl, sr);
    gather_kernel<true><<<N, 256, 0, stream>>>(h_buf, rp, col, sl, sr, out);
}

// Round 2
// 554.940 us; speedup vs baseline: 1.1074x; 1.1074x over previous
//
#include <hip/hip_runtime.h>
#include <hip/hip_bf16.h>

// Problem constants
#define NN 50000
#define EE 800000
#define HH 4
#define DD 64
#define HD 256
#define DIN 128

// ---------------- CSR build ----------------

__global__ void hist_kernel(const int* __restrict__ e0, int* __restrict__ cnt, int E) {
    int i = blockIdx.x * 256 + threadIdx.x;
    if (i < E) atomicAdd(&cnt[e0[i]], 1);
}

// 3-phase multi-block scan: A) per-block inclusive scan + totals, B) scan totals, C) combine
__global__ __launch_bounds__(1024) void scanA_kernel(const int* __restrict__ cnt,
                                                     int* __restrict__ incl,
                                                     int* __restrict__ tot, int N) {
    __shared__ int buf[2][1024];
    int b = blockIdx.x, t = threadIdx.x;
    int i = b * 1024 + t;
    int v = (i < N) ? cnt[i] : 0;
    buf[0][t] = v;
    __syncthreads();
    int sel = 0;
    for (int off = 1; off < 1024; off <<= 1) {
        int nv = buf[sel][t];
        if (t >= off) nv += buf[sel][t - off];
        buf[sel ^ 1][t] = nv;
        __syncthreads();
        sel ^= 1;
    }
    if (i < N) incl[i] = buf[sel][t];
    if (t == 1023) tot[b] = buf[sel][1023];
}

__global__ void scanB_kernel(int* __restrict__ tot, int nb) {
    if (threadIdx.x == 0) {
        int s = 0;
        for (int b = 0; b < nb; ++b) {
            int v = tot[b];
            tot[b] = s;
            s += v;
        }
    }
}

__global__ void scanC_kernel(const int* __restrict__ incl, const int* __restrict__ tot,
                             const int* __restrict__ cnt, int* __restrict__ rp,
                             int* __restrict__ cur, int N) {
    int i = blockIdx.x * 256 + threadIdx.x;
    if (i == 0) rp[0] = 0;
    if (i < N) {
        int e = incl[i] + tot[i >> 10];
        rp[i + 1] = e;
        cur[i] = e - cnt[i];
    }
}

__global__ void scatter_kernel(const int* __restrict__ e0, const int* __restrict__ e1,
                               int* __restrict__ cur, int* __restrict__ col, int E) {
    int i = blockIdx.x * 256 + threadIdx.x;
    if (i < E) {
        int pos = atomicAdd(&cur[e0[i]], 1);
        col[pos] = e1[i];
    }
}

// ---------------- GEMM: Y[n][m] = sum_k X[n][k]*W[m][k] + b[m] ----------------
// 128x128 tile, BK=16, 256 threads, 8x8 microtile, f32 vector FMA.

__global__ __launch_bounds__(256) void gemm_bias(const float* __restrict__ X,
                                                 const float* __restrict__ W,
                                                 const float* __restrict__ bias,
                                                 float* __restrict__ Y,
                                                 int Nrows, int K, int M) {
    __shared__ float As[16][132];
    __shared__ float Bs[16][132];
    const int t = threadIdx.x;
    const int tx = t & 15, ty = t >> 4;
    const int row0 = blockIdx.y * 128;
    const int col0 = blockIdx.x * 128;
    float acc[8][8] = {};

    for (int k0 = 0; k0 < K; k0 += 16) {
        int m = t >> 1;          // 0..127
        int kq = (t & 1) * 8;    // 0 or 8
        int r = row0 + m;
        float4 a0 = make_float4(0.f, 0.f, 0.f, 0.f), a1 = a0;
        if (r < Nrows) {
            a0 = *(const float4*)(X + (size_t)r * K + k0 + kq);
            a1 = *(const float4*)(X + (size_t)r * K + k0 + kq + 4);
        }
        As[kq + 0][m] = a0.x; As[kq + 1][m] = a0.y;
        As[kq + 2][m] = a0.z; As[kq + 3][m] = a0.w;
        As[kq + 4][m] = a1.x; As[kq + 5][m] = a1.y;
        As[kq + 6][m] = a1.z; As[kq + 7][m] = a1.w;
        float4 b0v = *(const float4*)(W + (size_t)(col0 + m) * K + k0 + kq);
        float4 b1v = *(const float4*)(W + (size_t)(col0 + m) * K + k0 + kq + 4);
        Bs[kq + 0][m] = b0v.x; Bs[kq + 1][m] = b0v.y;
        Bs[kq + 2][m] = b0v.z; Bs[kq + 3][m] = b0v.w;
        Bs[kq + 4][m] = b1v.x; Bs[kq + 5][m] = b1v.y;
        Bs[kq + 6][m] = b1v.z; Bs[kq + 7][m] = b1v.w;
        __syncthreads();
#pragma unroll
        for (int k = 0; k < 16; ++k) {
            float a[8], b[8];
            *(float4*)&a[0] = *(const float4*)&As[k][ty * 8];
            *(float4*)&a[4] = *(const float4*)&As[k][ty * 8 + 4];
            *(float4*)&b[0] = *(const float4*)&Bs[k][tx * 8];
            *(float4*)&b[4] = *(const float4*)&Bs[k][tx * 8 + 4];
#pragma unroll
            for (int i = 0; i < 8; ++i)
#pragma unroll
                for (int j = 0; j < 8; ++j) acc[i][j] = fmaf(a[i], b[j], acc[i][j]);
        }
        __syncthreads();
    }
#pragma unroll
    for (int i = 0; i < 8; ++i) {
        int r = row0 + ty * 8 + i;
        if (r < Nrows) {
#pragma unroll
            for (int j = 0; j < 8; j += 4) {
                int c = col0 + tx * 8 + j;
                float4 v;
                v.x = acc[i][j + 0] + bias[c + 0];
                v.y = acc[i][j + 1] + bias[c + 1];
                v.z = acc[i][j + 2] + bias[c + 2];
                v.w = acc[i][j + 3] + bias[c + 3];
                *(float4*)(Y + (size_t)r * M + c) = v;
            }
        }
    }
}

// ---------------- per-node attention scores ----------------

__global__ __launch_bounds__(256) void scores_kernel(const float* __restrict__ hbuf,
                                                     const float* __restrict__ att,
                                                     float* __restrict__ sl,
                                                     float* __restrict__ sr) {
    int n = blockIdx.x;
    int t = threadIdx.x;
    int hh = t >> 6, d = t & 63;
    float v = hbuf[(size_t)n * HD + t];
    float pl = v * att[hh * 2 * DD + d];
    float pr = v * att[hh * 2 * DD + DD + d];
    pl = pl > 0.f ? pl : 0.01f * pl;
    pr = pr > 0.f ? pr : 0.01f * pr;
#pragma unroll
    for (int m = 32; m > 0; m >>= 1) {
        pl += __shfl_xor(pl, m);
        pr += __shfl_xor(pr, m);
    }
    if (d == 0) {
        sl[n * HH + hh] = pl;
        sr[n * HH + hh] = pr;
    }
}

// ---------------- gather aggregation (one node per block) ----------------
// Scores computed ONCE per (edge, head) into LDS; inner loop is pure
// broadcast-LDS + coalesced global load + fmac.
// FINAL=false: fused LayerNorm + LeakyReLU epilogue (writes N x 256)
// FINAL=true : head-mean epilogue (writes N x 64)

template <bool FINAL>
__global__ __launch_bounds__(256) void gather_kernel(const float* __restrict__ hbuf,
                                                     const int* __restrict__ rp,
                                                     const int* __restrict__ col,
                                                     const float* __restrict__ sl,
                                                     const float* __restrict__ sr,
                                                     const float* __restrict__ gamma,
                                                     const float* __restrict__ beta,
                                                     float* __restrict__ out) {
    int n = blockIdx.x;
    int t = threadIdx.x;
    int hh = t >> 6;    // head of this thread
    int j64 = t & 63;   // edge slot within chunk for staging
    int start = rp[n], end = rp[n + 1];
    float my_sl = sl[n * HH + hh];

    __shared__ int cbuf[64];
    __shared__ float svbuf[64 * HH];

    float acc = 0.f, den = 0.f;
    for (int base = start; base < end; base += 64) {
        int m = end - base;
        if (m > 64) m = 64;
        __syncthreads();
        if (j64 < m) {
            int src = col[base + j64];
            if (hh == 0) cbuf[j64] = src;
            float sv = __expf((my_sl + sr[src * HH + hh]) * 0.0078125f);  // 1/(2*64)
            svbuf[j64 * HH + hh] = sv;
        }
        __syncthreads();
#pragma unroll 4
        for (int j = 0; j < m; ++j) {
            int src = cbuf[j];
            float sv = svbuf[j * HH + hh];
            acc = fmaf(hbuf[(size_t)src * HD + t], sv, acc);
            den += sv;
        }
    }
    float r = acc / den;

    if (!FINAL) {
        // fused LayerNorm + LeakyReLU: each thread holds element t of the row
        __shared__ float red[8];
        int wave = t >> 6, lane = t & 63;
        float s = r;
#pragma unroll
        for (int m2 = 32; m2 > 0; m2 >>= 1) s += __shfl_xor(s, m2);
        if (lane == 0) red[wave] = s;
        __syncthreads();
        float mu = (red[0] + red[1] + red[2] + red[3]) * (1.f / 256.f);
        float d = r - mu;
        float vs = d * d;
#pragma unroll
        for (int m2 = 32; m2 > 0; m2 >>= 1) vs += __shfl_xor(vs, m2);
        if (lane == 0) red[4 + wave] = vs;
        __syncthreads();
        float var = (red[4] + red[5] + red[6] + red[7]) * (1.f / 256.f);
        float y = d * rsqrtf(var + 1e-5f) * gamma[t] + beta[t];
        y = y > 0.f ? y : 0.01f * y;
        out[(size_t)n * HD + t] = y;
    } else {
        __shared__ float red[256];
        red[t] = r;
        __syncthreads();
        if (t < DD)
            out[(size_t)n * DD + t] =
                0.25f * (red[t] + red[t + 64] + red[t + 128] + red[t + 192]);
    }
}

// ---------------- launch ----------------

extern "C" void kernel_launch(void* const* d_in, const int* in_sizes, int n_in,
                              void* d_out, int out_size, void* d_ws, size_t ws_size,
                              hipStream_t stream) {
    const float* x     = (const float*)d_in[0];
    const int*   ei    = (const int*)d_in[1];   // (2, E): e0 then e1
    const float* W0    = (const float*)d_in[2];
    const float* b0    = (const float*)d_in[3];
    const float* W1    = (const float*)d_in[4];
    const float* b1    = (const float*)d_in[5];
    const float* att0  = (const float*)d_in[6];
    const float* att1  = (const float*)d_in[7];
    const float* gamma = (const float*)d_in[8];
    const float* beta  = (const float*)d_in[9];
    float* out = (float*)d_out;

    const int N = NN, E = EE;

    float* h_buf = (float*)d_ws;                       // N*256
    float* a_buf = h_buf + (size_t)N * HD;             // N*256
    float* sl    = a_buf + (size_t)N * HD;             // N*4
    float* sr    = sl + (size_t)N * HH;                // N*4
    int*   cnt   = (int*)(sr + (size_t)N * HH);        // N
    int*   rp    = cnt + N;                            // N+1
    int*   cur   = rp + N + 1;                         // N
    int*   col   = cur + N;                            // E
    int*   incl  = col + E;                            // N
    int*   tot   = incl + N;                           // 64

    const int* e0 = ei;
    const int* e1 = ei + E;

    const int NB = (N + 1023) / 1024;  // 49

    // CSR build (same for both layers)
    hipMemsetAsync(cnt, 0, N * sizeof(int), stream);
    hist_kernel<<<(E + 255) / 256, 256, 0, stream>>>(e0, cnt, E);
    scanA_kernel<<<NB, 1024, 0, stream>>>(cnt, incl, tot, N);
    scanB_kernel<<<1, 64, 0, stream>>>(tot, NB);
    scanC_kernel<<<(N + 255) / 256, 256, 0, stream>>>(incl, tot, cnt, rp, cur, N);
    scatter_kernel<<<(E + 255) / 256, 256, 0, stream>>>(e0, e1, cur, col, E);

    // layer 0
    gemm_bias<<<dim3(HD / 128, (N + 127) / 128), 256, 0, stream>>>(x, W0, b0, h_buf, N, DIN, HD);
    scores_kernel<<<N, 256, 0, stream>>>(h_buf, att0, sl, sr);
    gather_kernel<false><<<N, 256, 0, stream>>>(h_buf, rp, col, sl, sr, gamma, beta, a_buf);

    // layer 1
    gemm_bias<<<dim3(HD / 128, (N + 127) / 128), 256, 0, stream>>>(a_buf, W1, b1, h_buf, N, HD, HD);
    scores_kernel<<<N, 256, 0, stream>>>(h_buf, att1, sl, sr);
    gather_kernel<true><<<N, 256, 0, stream>>>(h_buf, rp, col, sl, sr, gamma, beta, out);
}

// Round 4
// 495.718 us; speedup vs baseline: 1.2397x; 1.1195x over previous
//
#include <hip/hip_runtime.h>
#include <hip/hip_bf16.h>
#include <type_traits>

// Problem constants
#define NN 50000
#define EE 800000
#define HH 4
#define DD 64
#define HD 256
#define DIN 128

__device__ inline ushort f2bf(float x) {
    __hip_bfloat16 b = __float2bfloat16(x);
    return __builtin_bit_cast(ushort, b);
}
__device__ inline float bf2f(ushort u) {
    return __uint_as_float((uint)u << 16);
}

// ---------------- CSR build ----------------

__global__ void hist_kernel(const int* __restrict__ e0, int* __restrict__ cnt, int E) {
    int i = blockIdx.x * 256 + threadIdx.x;
    if (i < E) atomicAdd(&cnt[e0[i]], 1);
}

__global__ __launch_bounds__(1024) void scanA_kernel(const int* __restrict__ cnt,
                                                     int* __restrict__ incl,
                                                     int* __restrict__ tot, int N) {
    __shared__ int buf[2][1024];
    int b = blockIdx.x, t = threadIdx.x;
    int i = b * 1024 + t;
    int v = (i < N) ? cnt[i] : 0;
    buf[0][t] = v;
    __syncthreads();
    int sel = 0;
    for (int off = 1; off < 1024; off <<= 1) {
        int nv = buf[sel][t];
        if (t >= off) nv += buf[sel][t - off];
        buf[sel ^ 1][t] = nv;
        __syncthreads();
        sel ^= 1;
    }
    if (i < N) incl[i] = buf[sel][t];
    if (t == 1023) tot[b] = buf[sel][1023];
}

__global__ void scanB_kernel(int* __restrict__ tot, int nb) {
    if (threadIdx.x == 0) {
        int s = 0;
        for (int b = 0; b < nb; ++b) {
            int v = tot[b];
            tot[b] = s;
            s += v;
        }
    }
}

__global__ void scanC_kernel(const int* __restrict__ incl, const int* __restrict__ tot,
                             const int* __restrict__ cnt, int* __restrict__ rp,
                             int* __restrict__ cur, int N) {
    int i = blockIdx.x * 256 + threadIdx.x;
    if (i == 0) rp[0] = 0;
    if (i < N) {
        int e = incl[i] + tot[i >> 10];
        rp[i + 1] = e;
        cur[i] = e - cnt[i];
    }
}

__global__ void scatter_kernel(const int* __restrict__ e0, const int* __restrict__ e1,
                               int* __restrict__ cur, int* __restrict__ col, int E) {
    int i = blockIdx.x * 256 + threadIdx.x;
    if (i < E) {
        int pos = atomicAdd(&cur[e0[i]], 1);
        col[pos] = e1[i];
    }
}

// ---------------- GEMM: Y[n][m] = sum_k X[n][k]*W[m][k] + b[m] ----------------
// 128x128 tile, BK=16, 256 threads, 8x8 microtile, f32 vector FMA.
// OT = float (f32 out) or ushort (bf16 out).

template <typename OT>
__global__ __launch_bounds__(256) void gemm_bias(const float* __restrict__ X,
                                                 const float* __restrict__ W,
                                                 const float* __restrict__ bias,
                                                 OT* __restrict__ Y,
                                                 int Nrows, int K, int M) {
    __shared__ float As[16][132];
    __shared__ float Bs[16][132];
    const int t = threadIdx.x;
    const int tx = t & 15, ty = t >> 4;
    const int row0 = blockIdx.y * 128;
    const int col0 = blockIdx.x * 128;
    float acc[8][8] = {};

    for (int k0 = 0; k0 < K; k0 += 16) {
        int m = t >> 1;          // 0..127
        int kq = (t & 1) * 8;    // 0 or 8
        int r = row0 + m;
        float4 a0 = make_float4(0.f, 0.f, 0.f, 0.f), a1 = a0;
        if (r < Nrows) {
            a0 = *(const float4*)(X + (size_t)r * K + k0 + kq);
            a1 = *(const float4*)(X + (size_t)r * K + k0 + kq + 4);
        }
        As[kq + 0][m] = a0.x; As[kq + 1][m] = a0.y;
        As[kq + 2][m] = a0.z; As[kq + 3][m] = a0.w;
        As[kq + 4][m] = a1.x; As[kq + 5][m] = a1.y;
        As[kq + 6][m] = a1.z; As[kq + 7][m] = a1.w;
        float4 b0v = *(const float4*)(W + (size_t)(col0 + m) * K + k0 + kq);
        float4 b1v = *(const float4*)(W + (size_t)(col0 + m) * K + k0 + kq + 4);
        Bs[kq + 0][m] = b0v.x; Bs[kq + 1][m] = b0v.y;
        Bs[kq + 2][m] = b0v.z; Bs[kq + 3][m] = b0v.w;
        Bs[kq + 4][m] = b1v.x; Bs[kq + 5][m] = b1v.y;
        Bs[kq + 6][m] = b1v.z; Bs[kq + 7][m] = b1v.w;
        __syncthreads();
#pragma unroll
        for (int k = 0; k < 16; ++k) {
            float a[8], b[8];
            *(float4*)&a[0] = *(const float4*)&As[k][ty * 8];
            *(float4*)&a[4] = *(const float4*)&As[k][ty * 8 + 4];
            *(float4*)&b[0] = *(const float4*)&Bs[k][tx * 8];
            *(float4*)&b[4] = *(const float4*)&Bs[k][tx * 8 + 4];
#pragma unroll
            for (int i = 0; i < 8; ++i)
#pragma unroll
                for (int j = 0; j < 8; ++j) acc[i][j] = fmaf(a[i], b[j], acc[i][j]);
        }
        __syncthreads();
    }
#pragma unroll
    for (int i = 0; i < 8; ++i) {
        int r = row0 + ty * 8 + i;
        if (r < Nrows) {
            int c = col0 + tx * 8;
            float v[8];
#pragma unroll
            for (int j = 0; j < 8; ++j) v[j] = acc[i][j] + bias[c + j];
            if constexpr (std::is_same_v<OT, float>) {
                *(float4*)(Y + (size_t)r * M + c) = make_float4(v[0], v[1], v[2], v[3]);
                *(float4*)(Y + (size_t)r * M + c + 4) = make_float4(v[4], v[5], v[6], v[7]);
            } else {
                uint4 p;
                p.x = (uint)f2bf(v[0]) | ((uint)f2bf(v[1]) << 16);
                p.y = (uint)f2bf(v[2]) | ((uint)f2bf(v[3]) << 16);
                p.z = (uint)f2bf(v[4]) | ((uint)f2bf(v[5]) << 16);
                p.w = (uint)f2bf(v[6]) | ((uint)f2bf(v[7]) << 16);
                *(uint4*)((ushort*)Y + (size_t)r * M + c) = p;
            }
        }
    }
}

// ---------------- per-node attention scores ----------------

template <typename PT>
__global__ __launch_bounds__(256) void scores_kernel(const PT* __restrict__ hbuf,
                                                     const float* __restrict__ att,
                                                     float* __restrict__ sl,
                                                     float* __restrict__ sr) {
    int n = blockIdx.x;
    int t = threadIdx.x;
    int hh = t >> 6, d = t & 63;
    float v;
    if constexpr (std::is_same_v<PT, float>) {
        v = hbuf[(size_t)n * HD + t];
    } else {
        v = bf2f(((const ushort*)hbuf)[(size_t)n * HD + t]);
    }
    float pl = v * att[hh * 2 * DD + d];
    float pr = v * att[hh * 2 * DD + DD + d];
    pl = pl > 0.f ? pl : 0.01f * pl;
    pr = pr > 0.f ? pr : 0.01f * pr;
#pragma unroll
    for (int m = 32; m > 0; m >>= 1) {
        pl += __shfl_xor(pl, m);
        pr += __shfl_xor(pr, m);
    }
    if (d == 0) {
        sl[n * HH + hh] = pl;
        sr[n * HH + hh] = pr;
    }
}

// ---------------- gather aggregation (one WAVE per node) ----------------
// lane covers 4 consecutive elements d = lane*4..lane*4+3, head hh = lane>>4.
// Staging (per 64-edge chunk): lane j loads col/src, sr4, computes 4 exps,
// writes sv[j][0..3] with one b128; den accumulated in registers.
// Inner loop: 2 broadcast-class ds_reads + 1 dwordx4 load + 4 fmac.
// FINAL=false: fused LayerNorm+LeakyReLU epilogue. FINAL=true: head-mean.

template <bool FINAL, typename PT>
__global__ __launch_bounds__(256) void gather_kernel(const PT* __restrict__ hbuf,
                                                     const int* __restrict__ rp,
                                                     const int* __restrict__ col,
                                                     const float* __restrict__ sl,
                                                     const float* __restrict__ sr,
                                                     const float* __restrict__ gamma,
                                                     const float* __restrict__ beta,
                                                     float* __restrict__ out) {
    const int t = threadIdx.x;
    const int w = t >> 6;
    const int lane = t & 63;
    const int hh = lane >> 4;
    const int n = blockIdx.x * 4 + w;

    __shared__ int cb[4][64];
    __shared__ float sv[4][256];

    const int start = rp[n], end = rp[n + 1];
    const float4 sl4 = *(const float4*)(sl + n * HH);

    float acc0 = 0.f, acc1 = 0.f, acc2 = 0.f, acc3 = 0.f;
    float dn0 = 0.f, dn1 = 0.f, dn2 = 0.f, dn3 = 0.f;
    const float C = 0.0078125f;  // 1/(2*64)

    for (int base = start; base < end; base += 64) {
        int m = end - base;
        if (m > 64) m = 64;
        if (lane < m) {
            int src = col[base + lane];
            cb[w][lane] = src;
            float4 sr4 = *(const float4*)(sr + src * HH);
            float e0 = __expf((sl4.x + sr4.x) * C);
            float e1 = __expf((sl4.y + sr4.y) * C);
            float e2 = __expf((sl4.z + sr4.z) * C);
            float e3 = __expf((sl4.w + sr4.w) * C);
            dn0 += e0; dn1 += e1; dn2 += e2; dn3 += e3;
            *(float4*)&sv[w][lane * 4] = make_float4(e0, e1, e2, e3);
        }
        __builtin_amdgcn_wave_barrier();
#pragma unroll 4
        for (int j = 0; j < m; ++j) {
            int src = cb[w][j];
            float s = sv[w][j * 4 + hh];
            if constexpr (std::is_same_v<PT, float>) {
                float4 hv = *(const float4*)(hbuf + (size_t)src * HD + lane * 4);
                acc0 = fmaf(hv.x, s, acc0);
                acc1 = fmaf(hv.y, s, acc1);
                acc2 = fmaf(hv.z, s, acc2);
                acc3 = fmaf(hv.w, s, acc3);
            } else {
                ushort4 u = *(const ushort4*)((const ushort*)hbuf + (size_t)src * HD + lane * 4);
                acc0 = fmaf(bf2f(u.x), s, acc0);
                acc1 = fmaf(bf2f(u.y), s, acc1);
                acc2 = fmaf(bf2f(u.z), s, acc2);
                acc3 = fmaf(bf2f(u.w), s, acc3);
            }
        }
        __builtin_amdgcn_wave_barrier();
    }

    // wave-total denominators per head
#pragma unroll
    for (int m2 = 32; m2 > 0; m2 >>= 1) {
        dn0 += __shfl_xor(dn0, m2);
        dn1 += __shfl_xor(dn1, m2);
        dn2 += __shfl_xor(dn2, m2);
        dn3 += __shfl_xor(dn3, m2);
    }
    float den = hh == 0 ? dn0 : hh == 1 ? dn1 : hh == 2 ? dn2 : dn3;
    float inv = 1.f / den;
    float r0 = acc0 * inv, r1 = acc1 * inv, r2 = acc2 * inv, r3 = acc3 * inv;

    if (!FINAL) {
        // fused LayerNorm + LeakyReLU over the 256-elem row held by this wave
        float s = r0 + r1 + r2 + r3;
#pragma unroll
        for (int m2 = 32; m2 > 0; m2 >>= 1) s += __shfl_xor(s, m2);
        float mu = s * (1.f / 256.f);
        float d0 = r0 - mu, d1 = r1 - mu, d2 = r2 - mu, d3 = r3 - mu;
        float vs = d0 * d0 + d1 * d1 + d2 * d2 + d3 * d3;
#pragma unroll
        for (int m2 = 32; m2 > 0; m2 >>= 1) vs += __shfl_xor(vs, m2);
        float rs = rsqrtf(vs * (1.f / 256.f) + 1e-5f);
        float4 g = *(const float4*)(gamma + lane * 4);
        float4 bb = *(const float4*)(beta + lane * 4);
        float y0 = d0 * rs * g.x + bb.x;
        float y1 = d1 * rs * g.y + bb.y;
        float y2 = d2 * rs * g.z + bb.z;
        float y3 = d3 * rs * g.w + bb.w;
        y0 = y0 > 0.f ? y0 : 0.01f * y0;
        y1 = y1 > 0.f ? y1 : 0.01f * y1;
        y2 = y2 > 0.f ? y2 : 0.01f * y2;
        y3 = y3 > 0.f ? y3 : 0.01f * y3;
        *(float4*)(out + (size_t)n * HD + lane * 4) = make_float4(y0, y1, y2, y3);
    } else {
        // head-mean: lanes {c, c+16, c+32, c+48} hold same d-block, diff heads
        r0 += __shfl_xor(r0, 16); r0 += __shfl_xor(r0, 32);
        r1 += __shfl_xor(r1, 16); r1 += __shfl_xor(r1, 32);
        r2 += __shfl_xor(r2, 16); r2 += __shfl_xor(r2, 32);
        r3 += __shfl_xor(r3, 16); r3 += __shfl_xor(r3, 32);
        if (lane < 16) {
            *(float4*)(out + (size_t)n * DD + lane * 4) =
                make_float4(r0 * 0.25f, r1 * 0.25f, r2 * 0.25f, r3 * 0.25f);
        }
    }
}

// ---------------- launch ----------------

extern "C" void kernel_launch(void* const* d_in, const int* in_sizes, int n_in,
                              void* d_out, int out_size, void* d_ws, size_t ws_size,
                              hipStream_t stream) {
    const float* x     = (const float*)d_in[0];
    const int*   ei    = (const int*)d_in[1];   // (2, E): e0 then e1
    const float* W0    = (const float*)d_in[2];
    const float* b0    = (const float*)d_in[3];
    const float* W1    = (const float*)d_in[4];
    const float* b1    = (const float*)d_in[5];
    const float* att0  = (const float*)d_in[6];
    const float* att1  = (const float*)d_in[7];
    const float* gamma = (const float*)d_in[8];
    const float* beta  = (const float*)d_in[9];
    float* out = (float*)d_out;

    const int N = NN, E = EE;

    float* h_buf = (float*)d_ws;                       // N*256 f32
    float* a_buf = h_buf + (size_t)N * HD;             // N*256 f32
    float* sl    = a_buf + (size_t)N * HD;             // N*4
    float* sr    = sl + (size_t)N * HH;                // N*4
    int*   cnt   = (int*)(sr + (size_t)N * HH);        // N
    int*   rp    = cnt + N;                            // N+1
    int*   cur   = rp + N + 1;                         // N
    int*   col   = cur + N;                            // E
    int*   incl  = col + E;                            // N
    int*   tot   = incl + N;                           // 64
    ushort* hb   = (ushort*)h_buf;                     // layer-2 h, bf16, reuses h_buf

    const int* e0 = ei;
    const int* e1 = ei + E;

    const int NB = (N + 1023) / 1024;  // 49

    // CSR build (same for both layers)
    hipMemsetAsync(cnt, 0, N * sizeof(int), stream);
    hist_kernel<<<(E + 255) / 256, 256, 0, stream>>>(e0, cnt, E);
    scanA_kernel<<<NB, 1024, 0, stream>>>(cnt, incl, tot, N);
    scanB_kernel<<<1, 64, 0, stream>>>(tot, NB);
    scanC_kernel<<<(N + 255) / 256, 256, 0, stream>>>(incl, tot, cnt, rp, cur, N);
    scatter_kernel<<<(E + 255) / 256, 256, 0, stream>>>(e0, e1, cur, col, E);

    // layer 0 (f32 payload)
    gemm_bias<float><<<dim3(HD / 128, (N + 127) / 128), 256, 0, stream>>>(x, W0, b0, h_buf, N, DIN, HD);
    scores_kernel<float><<<N, 256, 0, stream>>>(h_buf, att0, sl, sr);
    gather_kernel<false, float><<<N / 4, 256, 0, stream>>>(h_buf, rp, col, sl, sr, gamma, beta, a_buf);

    // layer 1 (bf16 payload; h_buf space reused as bf16)
    gemm_bias<ushort><<<dim3(HD / 128, (N + 127) / 128), 256, 0, stream>>>(a_buf, W1, b1, hb, N, HD, HD);
    scores_kernel<ushort><<<N, 256, 0, stream>>>(hb, att1, sl, sr);
    gather_kernel<true, ushort><<<N / 4, 256, 0, stream>>>(hb, rp, col, sl, sr, gamma, beta, out);
}

// Round 5
// 417.013 us; speedup vs baseline: 1.4737x; 1.1887x over previous
//
#include <hip/hip_runtime.h>
#include <hip/hip_bf16.h>
#include <type_traits>

// Problem constants
#define NN 50000
#define EE 800000
#define HH 4
#define DD 64
#define HD 256
#define DIN 128

__device__ inline ushort f2bf(float x) {
    __hip_bfloat16 b = __float2bfloat16(x);
    return __builtin_bit_cast(ushort, b);
}
__device__ inline float bf2f(ushort u) {
    return __uint_as_float((uint)u << 16);
}

// ---------------- CSR build ----------------

__global__ void hist_kernel(const int* __restrict__ e0, int* __restrict__ cnt, int E) {
    int i = blockIdx.x * 256 + threadIdx.x;
    if (i < E) atomicAdd(&cnt[e0[i]], 1);
}

__global__ __launch_bounds__(1024) void scanA_kernel(const int* __restrict__ cnt,
                                                     int* __restrict__ incl,
                                                     int* __restrict__ tot, int N) {
    __shared__ int buf[2][1024];
    int b = blockIdx.x, t = threadIdx.x;
    int i = b * 1024 + t;
    int v = (i < N) ? cnt[i] : 0;
    buf[0][t] = v;
    __syncthreads();
    int sel = 0;
    for (int off = 1; off < 1024; off <<= 1) {
        int nv = buf[sel][t];
        if (t >= off) nv += buf[sel][t - off];
        buf[sel ^ 1][t] = nv;
        __syncthreads();
        sel ^= 1;
    }
    if (i < N) incl[i] = buf[sel][t];
    if (t == 1023) tot[b] = buf[sel][1023];
}

__global__ void scanB_kernel(int* __restrict__ tot, int nb) {
    if (threadIdx.x == 0) {
        int s = 0;
        for (int b = 0; b < nb; ++b) {
            int v = tot[b];
            tot[b] = s;
            s += v;
        }
    }
}

__global__ void scanC_kernel(const int* __restrict__ incl, const int* __restrict__ tot,
                             const int* __restrict__ cnt, int* __restrict__ rp,
                             int* __restrict__ cur, int N) {
    int i = blockIdx.x * 256 + threadIdx.x;
    if (i == 0) rp[0] = 0;
    if (i < N) {
        int e = incl[i] + tot[i >> 10];
        rp[i + 1] = e;
        cur[i] = e - cnt[i];
    }
}

__global__ void scatter_kernel(const int* __restrict__ e0, const int* __restrict__ e1,
                               int* __restrict__ cur, int* __restrict__ col, int E) {
    int i = blockIdx.x * 256 + threadIdx.x;
    if (i < E) {
        int pos = atomicAdd(&cur[e0[i]], 1);
        col[pos] = e1[i];
    }
}

// ---------------- GEMM: Y[n][m] = sum_k X[n][k]*W[m][k] + b[m] ----------------
// 128x128 tile, BK=16, 256 threads, 8x8 microtile, f32 vector FMA.
// Output always bf16 (ushort).

__global__ __launch_bounds__(256) void gemm_bias(const float* __restrict__ X,
                                                 const float* __restrict__ W,
                                                 const float* __restrict__ bias,
                                                 ushort* __restrict__ Y,
                                                 int Nrows, int K, int M) {
    __shared__ float As[16][132];
    __shared__ float Bs[16][132];
    const int t = threadIdx.x;
    const int tx = t & 15, ty = t >> 4;
    const int row0 = blockIdx.y * 128;
    const int col0 = blockIdx.x * 128;
    float acc[8][8] = {};

    for (int k0 = 0; k0 < K; k0 += 16) {
        int m = t >> 1;          // 0..127
        int kq = (t & 1) * 8;    // 0 or 8
        int r = row0 + m;
        float4 a0 = make_float4(0.f, 0.f, 0.f, 0.f), a1 = a0;
        if (r < Nrows) {
            a0 = *(const float4*)(X + (size_t)r * K + k0 + kq);
            a1 = *(const float4*)(X + (size_t)r * K + k0 + kq + 4);
        }
        As[kq + 0][m] = a0.x; As[kq + 1][m] = a0.y;
        As[kq + 2][m] = a0.z; As[kq + 3][m] = a0.w;
        As[kq + 4][m] = a1.x; As[kq + 5][m] = a1.y;
        As[kq + 6][m] = a1.z; As[kq + 7][m] = a1.w;
        float4 b0v = *(const float4*)(W + (size_t)(col0 + m) * K + k0 + kq);
        float4 b1v = *(const float4*)(W + (size_t)(col0 + m) * K + k0 + kq + 4);
        Bs[kq + 0][m] = b0v.x; Bs[kq + 1][m] = b0v.y;
        Bs[kq + 2][m] = b0v.z; Bs[kq + 3][m] = b0v.w;
        Bs[kq + 4][m] = b1v.x; Bs[kq + 5][m] = b1v.y;
        Bs[kq + 6][m] = b1v.z; Bs[kq + 7][m] = b1v.w;
        __syncthreads();
#pragma unroll
        for (int k = 0; k < 16; ++k) {
            float a[8], b[8];
            *(float4*)&a[0] = *(const float4*)&As[k][ty * 8];
            *(float4*)&a[4] = *(const float4*)&As[k][ty * 8 + 4];
            *(float4*)&b[0] = *(const float4*)&Bs[k][tx * 8];
            *(float4*)&b[4] = *(const float4*)&Bs[k][tx * 8 + 4];
#pragma unroll
            for (int i = 0; i < 8; ++i)
#pragma unroll
                for (int j = 0; j < 8; ++j) acc[i][j] = fmaf(a[i], b[j], acc[i][j]);
        }
        __syncthreads();
    }
#pragma unroll
    for (int i = 0; i < 8; ++i) {
        int r = row0 + ty * 8 + i;
        if (r < Nrows) {
            int c = col0 + tx * 8;
            float v[8];
#pragma unroll
            for (int j = 0; j < 8; ++j) v[j] = acc[i][j] + bias[c + j];
            uint4 p;
            p.x = (uint)f2bf(v[0]) | ((uint)f2bf(v[1]) << 16);
            p.y = (uint)f2bf(v[2]) | ((uint)f2bf(v[3]) << 16);
            p.z = (uint)f2bf(v[4]) | ((uint)f2bf(v[5]) << 16);
            p.w = (uint)f2bf(v[6]) | ((uint)f2bf(v[7]) << 16);
            *(uint4*)(Y + (size_t)r * M + c) = p;
        }
    }
}

// ---------------- per-node attention scores (wave per node, 4 nodes/block) ----

__global__ __launch_bounds__(256) void scores_kernel(const ushort* __restrict__ hbuf,
                                                     const float* __restrict__ att,
                                                     float* __restrict__ sl,
                                                     float* __restrict__ sr) {
    const int t = threadIdx.x;
    const int w = t >> 6;
    const int lane = t & 63;
    const int hh = lane >> 4;
    const int dq = (lane & 15) * 4;  // d offset within head
    const int n = blockIdx.x * 4 + w;

    ushort4 u = *(const ushort4*)(hbuf + (size_t)n * HD + lane * 4);
    float4 al = *(const float4*)(att + hh * 2 * DD + dq);
    float4 ar = *(const float4*)(att + hh * 2 * DD + DD + dq);
    float v0 = bf2f(u.x), v1 = bf2f(u.y), v2 = bf2f(u.z), v3 = bf2f(u.w);

    float p;
    float pl, pr;
    p = v0 * al.x; pl  = p > 0.f ? p : 0.01f * p;
    p = v1 * al.y; pl += p > 0.f ? p : 0.01f * p;
    p = v2 * al.z; pl += p > 0.f ? p : 0.01f * p;
    p = v3 * al.w; pl += p > 0.f ? p : 0.01f * p;
    p = v0 * ar.x; pr  = p > 0.f ? p : 0.01f * p;
    p = v1 * ar.y; pr += p > 0.f ? p : 0.01f * p;
    p = v2 * ar.z; pr += p > 0.f ? p : 0.01f * p;
    p = v3 * ar.w; pr += p > 0.f ? p : 0.01f * p;

#pragma unroll
    for (int m = 1; m < 16; m <<= 1) {
        pl += __shfl_xor(pl, m);
        pr += __shfl_xor(pr, m);
    }
    if ((lane & 15) == 0) {
        sl[n * HH + hh] = pl;
        sr[n * HH + hh] = pr;
    }
}

// ---------------- gather aggregation (one WAVE per node, bf16 payload) -------
// lane covers 4 consecutive elements d = lane*4..lane*4+3, head hh = lane>>4.
// FINAL=false: fused LayerNorm+LeakyReLU epilogue (f32 out, N x 256).
// FINAL=true : head-mean epilogue (f32 out, N x 64).

template <bool FINAL>
__global__ __launch_bounds__(256) void gather_kernel(const ushort* __restrict__ hbuf,
                                                     const int* __restrict__ rp,
                                                     const int* __restrict__ col,
                                                     const float* __restrict__ sl,
                                                     const float* __restrict__ sr,
                                                     const float* __restrict__ gamma,
                                                     const float* __restrict__ beta,
                                                     float* __restrict__ out) {
    const int t = threadIdx.x;
    const int w = t >> 6;
    const int lane = t & 63;
    const int hh = lane >> 4;
    const int n = blockIdx.x * 4 + w;

    __shared__ int cb[4][64];
    __shared__ float sv[4][256];

    const int start = rp[n], end = rp[n + 1];
    const float4 sl4 = *(const float4*)(sl + n * HH);

    float acc0 = 0.f, acc1 = 0.f, acc2 = 0.f, acc3 = 0.f;
    float dn0 = 0.f, dn1 = 0.f, dn2 = 0.f, dn3 = 0.f;
    const float C = 0.0078125f;  // 1/(2*64)

    for (int base = start; base < end; base += 64) {
        int m = end - base;
        if (m > 64) m = 64;
        if (lane < m) {
            int src = col[base + lane];
            cb[w][lane] = src;
            float4 sr4 = *(const float4*)(sr + src * HH);
            float e0 = __expf((sl4.x + sr4.x) * C);
            float e1 = __expf((sl4.y + sr4.y) * C);
            float e2 = __expf((sl4.z + sr4.z) * C);
            float e3 = __expf((sl4.w + sr4.w) * C);
            dn0 += e0; dn1 += e1; dn2 += e2; dn3 += e3;
            *(float4*)&sv[w][lane * 4] = make_float4(e0, e1, e2, e3);
        }
        __builtin_amdgcn_wave_barrier();
#pragma unroll 8
        for (int j = 0; j < m; ++j) {
            int src = cb[w][j];
            float s = sv[w][j * 4 + hh];
            ushort4 u = *(const ushort4*)(hbuf + (size_t)src * HD + lane * 4);
            acc0 = fmaf(bf2f(u.x), s, acc0);
            acc1 = fmaf(bf2f(u.y), s, acc1);
            acc2 = fmaf(bf2f(u.z), s, acc2);
            acc3 = fmaf(bf2f(u.w), s, acc3);
        }
        __builtin_amdgcn_wave_barrier();
    }

    // wave-total denominators per head
#pragma unroll
    for (int m2 = 32; m2 > 0; m2 >>= 1) {
        dn0 += __shfl_xor(dn0, m2);
        dn1 += __shfl_xor(dn1, m2);
        dn2 += __shfl_xor(dn2, m2);
        dn3 += __shfl_xor(dn3, m2);
    }
    float den = hh == 0 ? dn0 : hh == 1 ? dn1 : hh == 2 ? dn2 : dn3;
    float inv = 1.f / den;
    float r0 = acc0 * inv, r1 = acc1 * inv, r2 = acc2 * inv, r3 = acc3 * inv;

    if (!FINAL) {
        // fused LayerNorm + LeakyReLU over the 256-elem row held by this wave
        float s = r0 + r1 + r2 + r3;
#pragma unroll
        for (int m2 = 32; m2 > 0; m2 >>= 1) s += __shfl_xor(s, m2);
        float mu = s * (1.f / 256.f);
        float d0 = r0 - mu, d1 = r1 - mu, d2 = r2 - mu, d3 = r3 - mu;
        float vs = d0 * d0 + d1 * d1 + d2 * d2 + d3 * d3;
#pragma unroll
        for (int m2 = 32; m2 > 0; m2 >>= 1) vs += __shfl_xor(vs, m2);
        float rs = rsqrtf(vs * (1.f / 256.f) + 1e-5f);
        float4 g = *(const float4*)(gamma + lane * 4);
        float4 bb = *(const float4*)(beta + lane * 4);
        float y0 = d0 * rs * g.x + bb.x;
        float y1 = d1 * rs * g.y + bb.y;
        float y2 = d2 * rs * g.z + bb.z;
        float y3 = d3 * rs * g.w + bb.w;
        y0 = y0 > 0.f ? y0 : 0.01f * y0;
        y1 = y1 > 0.f ? y1 : 0.01f * y1;
        y2 = y2 > 0.f ? y2 : 0.01f * y2;
        y3 = y3 > 0.f ? y3 : 0.01f * y3;
        *(float4*)(out + (size_t)n * HD + lane * 4) = make_float4(y0, y1, y2, y3);
    } else {
        // head-mean: lanes {c, c+16, c+32, c+48} hold same d-block, diff heads
        r0 += __shfl_xor(r0, 16); r0 += __shfl_xor(r0, 32);
        r1 += __shfl_xor(r1, 16); r1 += __shfl_xor(r1, 32);
        r2 += __shfl_xor(r2, 16); r2 += __shfl_xor(r2, 32);
        r3 += __shfl_xor(r3, 16); r3 += __shfl_xor(r3, 32);
        if (lane < 16) {
            *(float4*)(out + (size_t)n * DD + lane * 4) =
                make_float4(r0 * 0.25f, r1 * 0.25f, r2 * 0.25f, r3 * 0.25f);
        }
    }
}

// ---------------- launch ----------------

extern "C" void kernel_launch(void* const* d_in, const int* in_sizes, int n_in,
                              void* d_out, int out_size, void* d_ws, size_t ws_size,
                              hipStream_t stream) {
    const float* x     = (const float*)d_in[0];
    const int*   ei    = (const int*)d_in[1];   // (2, E): e0 then e1
    const float* W0    = (const float*)d_in[2];
    const float* b0    = (const float*)d_in[3];
    const float* W1    = (const float*)d_in[4];
    const float* b1    = (const float*)d_in[5];
    const float* att0  = (const float*)d_in[6];
    const float* att1  = (const float*)d_in[7];
    const float* gamma = (const float*)d_in[8];
    const float* beta  = (const float*)d_in[9];
    float* out = (float*)d_out;

    const int N = NN, E = EE;

    float* a_buf = (float*)d_ws;                       // N*256 f32 (LN output)
    ushort* hb0  = (ushort*)(a_buf + (size_t)N * HD);  // N*256 bf16
    ushort* hb1  = hb0 + (size_t)N * HD;               // N*256 bf16
    float* sl    = (float*)(hb1 + (size_t)N * HD);     // N*4
    float* sr    = sl + (size_t)N * HH;                // N*4
    int*   cnt   = (int*)(sr + (size_t)N * HH);        // N
    int*   rp    = cnt + N;                            // N+1
    int*   cur   = rp + N + 1;                         // N
    int*   col   = cur + N;                            // E
    int*   incl  = col + E;                            // N
    int*   tot   = incl + N;                           // 64

    const int* e0 = ei;
    const int* e1 = ei + E;

    const int NB = (N + 1023) / 1024;  // 49

    // CSR build (same for both layers)
    hipMemsetAsync(cnt, 0, N * sizeof(int), stream);
    hist_kernel<<<(E + 255) / 256, 256, 0, stream>>>(e0, cnt, E);
    scanA_kernel<<<NB, 1024, 0, stream>>>(cnt, incl, tot, N);
    scanB_kernel<<<1, 64, 0, stream>>>(tot, NB);
    scanC_kernel<<<(N + 255) / 256, 256, 0, stream>>>(incl, tot, cnt, rp, cur, N);
    scatter_kernel<<<(E + 255) / 256, 256, 0, stream>>>(e0, e1, cur, col, E);

    // layer 0 (bf16 payload)
    gemm_bias<<<dim3(HD / 128, (N + 127) / 128), 256, 0, stream>>>(x, W0, b0, hb0, N, DIN, HD);
    scores_kernel<<<N / 4, 256, 0, stream>>>(hb0, att0, sl, sr);
    gather_kernel<false><<<N / 4, 256, 0, stream>>>(hb0, rp, col, sl, sr, gamma, beta, a_buf);

    // layer 1 (bf16 payload)
    gemm_bias<<<dim3(HD / 128, (N + 127) / 128), 256, 0, stream>>>(a_buf, W1, b1, hb1, N, HD, HD);
    scores_kernel<<<N / 4, 256, 0, stream>>>(hb1, att1, sl, sr);
    gather_kernel<true><<<N / 4, 256, 0, stream>>>(hb1, rp, col, sl, sr, gamma, beta, out);
}